// Round 3
// baseline (5643.130 us; speedup 1.0000x reference)
//
#include <hip/hip_runtime.h>
#include <hip/hip_bf16.h>
#include <stdint.h>

// RNNPB via per-step MFMA GEMM (R14 = R13 + K-split wave pairs).
// Cost model (corrected): mfma_16x16x32_f16 ~19.4 SIMD-cyc -> MFMA 621 cyc/SIMD/step;
// LDS pipe ~870 cyc/CU/step (64 b128 reads + writes). Step = 1141 -> co-bound,
// LDS is the taller pole. R14 halves B-panel reads while KEEPING 2 waves/SIMD
// (R12 lesson): waves (P, P+4) share tiles {4P..4P+3}; low wave = K[0,128)
// (frags 0-3), high = K[128,256) (frags 4-7). Partials exchanged via an 8KB
// LDS Pbuf in f16 (lane-contiguous b64, conflict-free) + a second barrier;
// each wave combines own(f32)+partner(f16) for 2 tiles and writes h.
// Epilogue mapping = R11's with w -> vw = 2P+role (wave7 still owns out tile).
//   h_{t+1} = relu(M h_t + W1d d_{t+1} + cb' + W1p pb),  out_t = W2d h_t + b2d
// A (f16, 256x256): rows [0,240) h, [240,246) out (W2d); cols [0,240) M/W2d,
//   [240,246) W1d, 246 bias, 247/248 W1p, 249+ zero.
// B panel frag-major: Hx[buf][frag 0..7][lane 0..63][8 halves]; element (k,n):
//   frag k>>5, lane ((k&31)>>3)*16+n, sub k&7.
// 2 blocks x 16 batches; 8 waves; d-input via 96-lane register FIFO (waves 0-1).

#define T_STEPS 8192
#define HID     240
#define CTX     180
#define KTOT    256
#define HXBUF   4096                       // halves/buffer: 8 frags x 64 lanes x 8
#define PBUF    4096                       // halves: 8 wave-regions x 2 slots x 256
#define A_HALVES (256*256)
#define SCRATCH_BYTES (A_HALVES*2 + 16)

typedef __hip_bfloat16 bf16;
typedef _Float16 f16;
typedef _Float16 half8  __attribute__((ext_vector_type(8)));
typedef _Float16 half4v __attribute__((ext_vector_type(4)));
typedef float    f32x4  __attribute__((ext_vector_type(4)));
typedef float    f32x2  __attribute__((ext_vector_type(2)));

#define MFMA16(A,B,C) __builtin_amdgcn_mfma_f32_16x16x32_f16((A),(B),(C),0,0,0)

__device__ __forceinline__ float ldin(const void* p, long i, bool f32) {
    return f32 ? ((const float*)p)[i] : __bfloat162float(((const bf16*)p)[i]);
}
__device__ __forceinline__ unsigned pkbf(float a, float b) {
    unsigned ua = (unsigned)__builtin_bit_cast(unsigned short, __float2bfloat16(a));
    unsigned ub = (unsigned)__builtin_bit_cast(unsigned short, __float2bfloat16(b));
    return ua | (ub << 16);
}
// LDS-ordering barrier WITHOUT vmem drain (out-stores/d-loads stay in flight)
__device__ __forceinline__ void barrier_lds() {
    asm volatile("s_waitcnt lgkmcnt(0)\n\ts_barrier" ::: "memory");
}

// fp32 arrays: low half-words are random mantissa (huge-as-bf16 w.p. ~0.45/word)
// or all-zero (bf16-grid). Real bf16 arrays: neither. (Verified R2-R10: bf16 path.)
__global__ __launch_bounds__(64) void detect_dtype(const void* data, int* flag) {
    unsigned int w  = ((const unsigned int*)data)[threadIdx.x];
    unsigned int lo = w & 0xFFFFu;
    unsigned int ex = (lo >> 7) & 0xFFu;
    unsigned long long huge = __ballot(ex >= 0x8Eu);
    unsigned long long zero = __ballot(lo == 0u);
    if (threadIdx.x == 0) *flag = (huge != 0ull || zero == ~0ull) ? 1 : 0;
}

// ---------------- build augmented A (f16) ----------------
__global__ __launch_bounds__(256) void build_A(
    const void* __restrict__ W1d, const void* __restrict__ b1d,
    const void* __restrict__ W1p, const void* __restrict__ b1p,
    const void* __restrict__ W1c, const void* __restrict__ b1c,
    const void* __restrict__ W2d, const void* __restrict__ b2d,
    const void* __restrict__ W2c, const void* __restrict__ b2c,
    f16* __restrict__ Aa, const int* __restrict__ flagp)
{
    const bool f32 = (*flagp != 0);
    int idx = blockIdx.x*256 + threadIdx.x;
    int r = idx >> 8, k = idx & 255;
    float v = 0.f;
    if (r < HID) {
        if (k < HID) {                           // M = W1c @ W2c
            float acc = 0.f;
            for (int c = 0; c < CTX; ++c)
                acc = fmaf(ldin(W1c, r*CTX+c, f32), ldin(W2c, c*HID+k, f32), acc);
            v = acc;
        } else if (k < 246) {                    // W1d columns
            v = ldin(W1d, r*6 + (k-240), f32);
        } else if (k == 246) {                   // bias: b1d+b1c+b1p + W1c@b2c
            float m0 = 0.f;
            for (int c = 0; c < CTX; ++c)
                m0 = fmaf(ldin(W1c, r*CTX+c, f32), ldin(b2c, c, f32), m0);
            v = ldin(b1d, r, f32) + ldin(b1c, r, f32) + ldin(b1p, r, f32) + m0;
        } else if (k <= 248) {                   // W1p columns
            v = ldin(W1p, r*2 + (k-247), f32);
        }
    } else if (r < 246) {                        // out rows
        int o = r - 240;
        if (k < HID)       v = ldin(W2d, o*HID + k, f32);
        else if (k == 246) v = ldin(b2d, o, f32);
    }
    Aa[idx] = (f16)v;
}

// frag-major Hx offset for scalar element (row j, col n), within one buffer
__device__ __forceinline__ int hx_off(int j, int n) {
    return (j >> 5)*512 + ((((j & 31) >> 3))*16 + n)*8 + (j & 7);
}

// ---------------- per-step MFMA recurrent kernel: 2 blocks x 16 batches ----------------
__global__ __launch_bounds__(512, 2) void rnn_mfma(
    const void* __restrict__ data,   // [30][6][8192]
    const void* __restrict__ b1d, const void* __restrict__ W1p,
    const void* __restrict__ b1p, const void* __restrict__ b1c,
    const void* __restrict__ W1d, const void* __restrict__ pb,
    const f16* __restrict__ Aa, const int* __restrict__ flagp,
    void* __restrict__ out)          // [30][8192][6]
{
    const bool f32 = (*flagp != 0);
    const int tid  = threadIdx.x;
    const int w    = tid >> 6;       // wave 0..7
    const int P    = w & 3;          // pair index (waves P and P+4 share tiles 4P..4P+3)
    const int role = w >> 2;         // 0 = K-low (frags 0-3), 1 = K-high (frags 4-7)
    const int vw   = P*2 + role;     // epilogue tile-pair: combines tiles {2vw, 2vw+1}
    const int l    = tid & 63;
    const int n16  = l & 15;
    const int quad = l >> 4;
    const int base = blockIdx.x * 16;
    const int bn   = base + n16;
    const bool bvalid = (bn < 30);

    __shared__ __align__(16) f16 Hx[2*HXBUF + PBUF];   // 24,576 B

    // ---- zero Hx panels (rows >248 and untouched slots must stay 0)
    {
        int* hz = (int*)Hx;
        for (int i = tid; i < HXBUF; i += 512) hz[i] = 0;    // 4096 ints = both buffers
    }
    __syncthreads();

    // ---- const rows 246/247/248 in both buffers
    if (tid < 32) {
        int bsel = tid >> 4, n = tid & 15;
        int nb = base + n; if (nb > 29) nb = 29;
        f16* buf = Hx + bsel*HXBUF;
        buf[3584 + (32+n)*8 + 6] = (f16)1.0f;
        buf[3584 + (32+n)*8 + 7] = (f16)ldin(pb, nb*2+0, f32);
        buf[3584 + (48+n)*8 + 0] = (f16)ldin(pb, nb*2+1, f32);
    }

    // ---- h_0 = relu(cb + W1d d_0)  into Hx[0]
    for (int p = tid; p < HID*16; p += 512) {
        int n = p / HID, j = p - n*HID;
        int nb = base + n; if (nb > 29) nb = 29;
        float s = ldin(b1d, j, f32) + ldin(b1c, j, f32) + ldin(b1p, j, f32)
                + ldin(W1p, j*2+0, f32)*ldin(pb, nb*2+0, f32)
                + ldin(W1p, j*2+1, f32)*ldin(pb, nb*2+1, f32);
        for (int d = 0; d < 6; ++d)
            s = fmaf(ldin(W1d, j*6+d, f32), ldin(data, ((long)nb*6+d)*T_STEPS, f32), s);
        Hx[hx_off(j, n)] = (f16)fmaxf(s, 0.f);
    }

    // ---- d-feed lane roles (tid<96 = waves 0-1): (pn, pd)
    const int pn = tid & 15, pd = tid >> 4;
    int pnb = base + pn; if (pnb > 29) pnb = 29;
    const long prow = ((long)pnb*6 + (pd < 6 ? pd : 0))*T_STEPS;
    const int  doff = 3584 + (32+pn)*8 + pd;     // row (240+pd), col pn

    // d_1 into Hx[0] rows 240..245
    if (tid < 96)
        Hx[doff] = (f16)ldin(data, prow + 1, f32);

    // d-FIFO preload: u0 = raw d[2] (consumed step 0), u1 = raw d[3] (step 1)
    unsigned u0 = 0, u1 = 0;
    if (tid < 96) {
        if (!f32) {
            u0 = ((const unsigned short*)data)[prow + 2];
            u1 = ((const unsigned short*)data)[prow + 3];
        } else {
            u0 = __builtin_bit_cast(unsigned, ((const float*)data)[prow + 2]);
            u1 = __builtin_bit_cast(unsigned, ((const float*)data)[prow + 3]);
        }
    }

    // ---- persistent A fragments: 16 NAMED half8 locals
    // tiles 4P+i (i=0..3), K-frags role*4+j (j=0..3); tile stride 16*KTOT=4096
    const f16* Ab = Aa + (size_t)((4*P)*16 + n16)*KTOT + role*128 + quad*8;
    half8 A00 = *(const half8*)(Ab +     0 +  0), A01 = *(const half8*)(Ab +     0 + 32);
    half8 A02 = *(const half8*)(Ab +     0 + 64), A03 = *(const half8*)(Ab +     0 + 96);
    half8 A10 = *(const half8*)(Ab +  4096 +  0), A11 = *(const half8*)(Ab +  4096 + 32);
    half8 A12 = *(const half8*)(Ab +  4096 + 64), A13 = *(const half8*)(Ab +  4096 + 96);
    half8 A20 = *(const half8*)(Ab +  8192 +  0), A21 = *(const half8*)(Ab +  8192 + 32);
    half8 A22 = *(const half8*)(Ab +  8192 + 64), A23 = *(const half8*)(Ab +  8192 + 96);
    half8 A30 = *(const half8*)(Ab + 12288 +  0), A31 = *(const half8*)(Ab + 12288 + 32);
    half8 A32 = *(const half8*)(Ab + 12288 + 64), A33 = *(const half8*)(Ab + 12288 + 96);
    // drain A reads before any wave can store into the (possible) d_out-tail scratch
    asm volatile("s_waitcnt vmcnt(0)" ::: "memory");
    __syncthreads();

    // ---- steady-state addressing
    // B reads: lane-contiguous, my K-half; frag j at +j*512, buffer at +cur*HXBUF
    const f16* hxread0 = Hx + role*2048 + l*8;
    // h-write: tile 2vw at +0, tile 2vw+1 at +256 (buffer select = +nxt*HXBUF)
    f16* hxw = Hx + vw*512 + ((quad>>1)*16 + n16)*8 + 4*(quad&1);
    // partial exchange buffer (f16): region per wave, 2 slots x 256 halves
    f16*       pwr = Hx + 2*HXBUF + (P*2 + role)*512     + l*4;   // my writes
    const f16* prd = Hx + 2*HXBUF + (P*2 + (role^1))*512 + l*4;   // partner reads

    for (int t2 = 0; t2 < T_STEPS; t2 += 2) {
        #pragma unroll
        for (int s = 0; s < 2; ++s) {
            const int t = t2 + s;
            const int cur = s, nxt = s ^ 1;      // compile-time parity

            // ---- d-feed (waves 0-1): write d_{t+2} -> Hx[nxt]; issue load d[t+4]
            if (tid < 96) {
                unsigned uc = (s == 0) ? u0 : u1;
                float dv = f32 ? __builtin_bit_cast(float, uc)
                               : __builtin_bit_cast(float, uc << 16);
                Hx[nxt*HXBUF + doff] = (f16)dv;
                long g = t + 4; if (g > T_STEPS-1) g = T_STEPS-1;
                unsigned un;
                if (!f32) un = ((const unsigned short*)data)[prow + g];
                else      un = __builtin_bit_cast(unsigned, ((const float*)data)[prow + g]);
                if (s == 0) u0 = un; else u1 = un;
            }

            // ---- B fragments (4, my K-half) + MFMA: 4 tiles x 4 frags, 4-way ILP
            const f16* hxc = hxread0 + cur*HXBUF;
            half8 b0 = *(const half8*)(hxc +    0);
            half8 b1 = *(const half8*)(hxc +  512);
            f32x4 c0 = {0.f,0.f,0.f,0.f}, c1 = {0.f,0.f,0.f,0.f};
            f32x4 c2 = {0.f,0.f,0.f,0.f}, c3 = {0.f,0.f,0.f,0.f};
            half8 b2 = *(const half8*)(hxc + 1024);
            c0 = MFMA16(A00, b0, c0);  c1 = MFMA16(A10, b0, c1);
            c2 = MFMA16(A20, b0, c2);  c3 = MFMA16(A30, b0, c3);
            half8 b3 = *(const half8*)(hxc + 1536);
            c0 = MFMA16(A01, b1, c0);  c1 = MFMA16(A11, b1, c1);
            c2 = MFMA16(A21, b1, c2);  c3 = MFMA16(A31, b1, c3);
            c0 = MFMA16(A02, b2, c0);  c1 = MFMA16(A12, b2, c1);
            c2 = MFMA16(A22, b2, c2);  c3 = MFMA16(A32, b2, c3);
            c0 = MFMA16(A03, b3, c0);  c1 = MFMA16(A13, b3, c1);
            c2 = MFMA16(A23, b3, c2);  c3 = MFMA16(A33, b3, c3);

            // ---- write the partials I do NOT combine (f16, lane-contiguous b64)
            if (role == 0) {                     // low combines tiles 0,1 -> writes 2,3
                half4v w0; w0.x=(f16)c2.x; w0.y=(f16)c2.y; w0.z=(f16)c2.z; w0.w=(f16)c2.w;
                half4v w1; w1.x=(f16)c3.x; w1.y=(f16)c3.y; w1.z=(f16)c3.z; w1.w=(f16)c3.w;
                *(half4v*)(pwr)       = w0;
                *(half4v*)(pwr + 256) = w1;
            } else {                             // high combines tiles 2,3 -> writes 0,1
                half4v w0; w0.x=(f16)c0.x; w0.y=(f16)c0.y; w0.z=(f16)c0.z; w0.w=(f16)c0.w;
                half4v w1; w1.x=(f16)c1.x; w1.y=(f16)c1.y; w1.z=(f16)c1.z; w1.w=(f16)c1.w;
                *(half4v*)(pwr)       = w0;
                *(half4v*)(pwr + 256) = w1;
            }
            barrier_lds();                       // bar2: partials visible

            // ---- read partner partials, combine own(f32)+partner(f16)
            half4v p0 = *(const half4v*)(prd);
            half4v p1 = *(const half4v*)(prd + 256);
            f32x4 o0 = (role == 0) ? c0 : c2;    // role is wave-uniform: scalar select
            f32x4 o1 = (role == 0) ? c1 : c3;

            // ---- epilogue: h rows -> relu -> Hx[nxt]; out rows (wave 7) -> global
            f16* hxn = hxw + nxt*HXBUF;
            {   // tile 2vw (always an h-tile: 2vw <= 14)
                half4v hv;
                hv.x = (f16)fmaxf(o0.x + (float)p0.x, 0.f);
                hv.y = (f16)fmaxf(o0.y + (float)p0.y, 0.f);
                hv.z = (f16)fmaxf(o0.z + (float)p0.z, 0.f);
                hv.w = (f16)fmaxf(o0.w + (float)p0.w, 0.f);
                *(half4v*)(hxn) = hv;
            }
            if (vw < 7) {                        // tile 2vw+1: h-tile
                half4v hv;
                hv.x = (f16)fmaxf(o1.x + (float)p1.x, 0.f);
                hv.y = (f16)fmaxf(o1.y + (float)p1.y, 0.f);
                hv.z = (f16)fmaxf(o1.z + (float)p1.z, 0.f);
                hv.w = (f16)fmaxf(o1.w + (float)p1.w, 0.f);
                *(half4v*)(hxn + 256) = hv;
            } else if (bvalid) {                 // wave 7, tile 15: out rows 240..247
                float v0 = o1.x + (float)p1.x, v1 = o1.y + (float)p1.y;
                float v2 = o1.z + (float)p1.z, v3 = o1.w + (float)p1.w;
                long ob = ((long)bn*T_STEPS + t)*6;
                if (quad == 0) {                               // out elems 0..3
                    if (!f32) {
                        bf16* op = (bf16*)out + ob;
                        *(unsigned*)(op)     = pkbf(v0, v1);
                        *(unsigned*)(op + 2) = pkbf(v2, v3);
                    } else {
                        float* op = (float*)out + ob;
                        f32x2 q0 = {v0, v1}; *(f32x2*)(op)     = q0;
                        f32x2 q1 = {v2, v3}; *(f32x2*)(op + 2) = q1;
                    }
                } else if (quad == 1) {                        // out elems 4,5
                    if (!f32) {
                        bf16* op = (bf16*)out + ob;
                        *(unsigned*)(op + 4) = pkbf(v0, v1);
                    } else {
                        float* op = (float*)out + ob;
                        f32x2 q0 = {v0, v1}; *(f32x2*)(op + 4) = q0;
                    }
                }
            }
            barrier_lds();                       // bar1: h/d writes visible for next step
        }
    }
}

extern "C" void kernel_launch(void* const* d_in, const int* in_sizes, int n_in,
                              void* d_out, int out_size, void* d_ws, size_t ws_size,
                              hipStream_t stream) {
    const void* data = d_in[0];
    const void* W1d  = d_in[1];
    const void* b1d  = d_in[2];
    const void* W1p  = d_in[3];
    const void* b1p  = d_in[4];
    const void* W1c  = d_in[5];
    const void* b1c  = d_in[6];
    const void* W2d  = d_in[7];
    const void* b2d  = d_in[8];
    const void* W2c  = d_in[9];
    const void* b2c  = d_in[10];
    const void* pb   = d_in[11];

    size_t need = SCRATCH_BYTES;
    char* scratch;
    if (ws_size >= need) {
        scratch = (char*)d_ws;
    } else {
        size_t out_bytes = (size_t)30*T_STEPS*6*sizeof(bf16);
        scratch = (char*)d_out + ((out_bytes - need) & ~(size_t)255);
    }
    f16* Aa    = (f16*)scratch;
    int* flagp = (int*)(scratch + A_HALVES*2);

    detect_dtype<<<1, 64, 0, stream>>>(data, flagp);
    build_A<<<A_HALVES/256, 256, 0, stream>>>(W1d, b1d, W1p, b1p, W1c, b1c,
                                              W2d, b2d, W2c, b2c, Aa, flagp);
    rnn_mfma<<<2, 512, 0, stream>>>(data, b1d, W1p, b1p, b1c, W1d, pb,
                                    Aa, flagp, d_out);
}

// Round 4
// 3652.933 us; speedup vs baseline: 1.5448x; 1.5448x over previous
//
#include <hip/hip_runtime.h>
#include <hip/hip_bf16.h>
#include <stdint.h>

// RNNPB via per-step MFMA GEMM (R15 = R13 + critical-path scheduling).
// Model (fits R11-R14): step = imperfect overlap of LDS drain (64 b128 x 12cyc
// = 768), MFMA (621/SIMD), read bubble (~120), epilogue/d-feed VALU (~100-200),
// barrier. R14's mid-step exchange regressed (+518 cyc); R13 conflict-fix was
// neutral (drain unchanged). R15 keeps R13's structure/layout and only
// reschedules: (1) all 8 ds_reads issue FIRST after the barrier; (2) the
// 120-cyc bubble is filled with d-feed + wave7's DEFERRED out-store (store for
// step t-1 happens in step t's read shadow; pend regs cross the barrier);
// (3) c0 consumes frags 0..7, c1 rotated 1..7,0 -> c0 finishes 2 slots early,
// its epilogue overlaps c1's tail MFMAs. d-load uses incremental 32-bit voffset.
//   h_{t+1} = relu(M h_t + W1d d_{t+1} + cb' + W1p pb),  out_t = W2d h_t + b2d
// A (f16, 256x256): rows [0,240) h, [240,246) out (W2d); cols [0,240) M/W2d,
//   [240,246) W1d, 246 bias, 247/248 W1p, 249+ zero.
// B panel frag-major: Hx[buf][frag 0..7][lane 0..63][8 halves]; element (k,n):
//   frag k>>5, lane ((k&31)>>3)*16+n, sub k&7.  Lane-contiguous b128 reads
//   (conflict-free); h-writes are one b64 per lane.
// 2 blocks x 16 batches; 8 waves (2/SIMD) x 2 row-tiles x 8 K-frags.
// d-input via 96-lane register FIFO (waves 0-1): one 2B L2-hot load per step.

#define T_STEPS 8192
#define HID     240
#define CTX     180
#define KTOT    256
#define HXBUF   4096                       // halves/buffer: 8 frags x 64 lanes x 8
#define A_HALVES (256*256)
#define SCRATCH_BYTES (A_HALVES*2 + 16)

typedef __hip_bfloat16 bf16;
typedef _Float16 f16;
typedef _Float16 half8  __attribute__((ext_vector_type(8)));
typedef _Float16 half4v __attribute__((ext_vector_type(4)));
typedef float    f32x4  __attribute__((ext_vector_type(4)));
typedef float    f32x2  __attribute__((ext_vector_type(2)));

#define MFMA16(A,B,C) __builtin_amdgcn_mfma_f32_16x16x32_f16((A),(B),(C),0,0,0)

__device__ __forceinline__ float ldin(const void* p, long i, bool f32) {
    return f32 ? ((const float*)p)[i] : __bfloat162float(((const bf16*)p)[i]);
}
__device__ __forceinline__ unsigned pkbf(float a, float b) {
    unsigned ua = (unsigned)__builtin_bit_cast(unsigned short, __float2bfloat16(a));
    unsigned ub = (unsigned)__builtin_bit_cast(unsigned short, __float2bfloat16(b));
    return ua | (ub << 16);
}
// LDS-ordering barrier WITHOUT vmem drain (out-stores/d-loads stay in flight)
__device__ __forceinline__ void barrier_lds() {
    asm volatile("s_waitcnt lgkmcnt(0)\n\ts_barrier" ::: "memory");
}

// deferred out-store: writes the 6 outputs of one step (wave 7, quads 0-1)
__device__ __forceinline__ void store_out(void* out, bool f32, int quad, long ob, f32x4 v) {
    if (quad == 0) {                                   // out elems 0..3
        if (!f32) {
            bf16* op = (bf16*)out + ob;
            *(unsigned*)(op)     = pkbf(v.x, v.y);
            *(unsigned*)(op + 2) = pkbf(v.z, v.w);
        } else {
            float* op = (float*)out + ob;
            f32x2 p0 = {v.x, v.y}; *(f32x2*)(op)     = p0;
            f32x2 p1 = {v.z, v.w}; *(f32x2*)(op + 2) = p1;
        }
    } else if (quad == 1) {                            // out elems 4,5
        if (!f32) {
            bf16* op = (bf16*)out + ob;
            *(unsigned*)(op + 4) = pkbf(v.x, v.y);
        } else {
            float* op = (float*)out + ob;
            f32x2 p0 = {v.x, v.y}; *(f32x2*)(op + 4) = p0;
        }
    }
}

// fp32 arrays: low half-words are random mantissa (huge-as-bf16 w.p. ~0.45/word)
// or all-zero (bf16-grid). Real bf16 arrays: neither. (Verified R2-R10: bf16 path.)
__global__ __launch_bounds__(64) void detect_dtype(const void* data, int* flag) {
    unsigned int w  = ((const unsigned int*)data)[threadIdx.x];
    unsigned int lo = w & 0xFFFFu;
    unsigned int ex = (lo >> 7) & 0xFFu;
    unsigned long long huge = __ballot(ex >= 0x8Eu);
    unsigned long long zero = __ballot(lo == 0u);
    if (threadIdx.x == 0) *flag = (huge != 0ull || zero == ~0ull) ? 1 : 0;
}

// ---------------- build augmented A (f16) ----------------
__global__ __launch_bounds__(256) void build_A(
    const void* __restrict__ W1d, const void* __restrict__ b1d,
    const void* __restrict__ W1p, const void* __restrict__ b1p,
    const void* __restrict__ W1c, const void* __restrict__ b1c,
    const void* __restrict__ W2d, const void* __restrict__ b2d,
    const void* __restrict__ W2c, const void* __restrict__ b2c,
    f16* __restrict__ Aa, const int* __restrict__ flagp)
{
    const bool f32 = (*flagp != 0);
    int idx = blockIdx.x*256 + threadIdx.x;
    int r = idx >> 8, k = idx & 255;
    float v = 0.f;
    if (r < HID) {
        if (k < HID) {                           // M = W1c @ W2c
            float acc = 0.f;
            for (int c = 0; c < CTX; ++c)
                acc = fmaf(ldin(W1c, r*CTX+c, f32), ldin(W2c, c*HID+k, f32), acc);
            v = acc;
        } else if (k < 246) {                    // W1d columns
            v = ldin(W1d, r*6 + (k-240), f32);
        } else if (k == 246) {                   // bias: b1d+b1c+b1p + W1c@b2c
            float m0 = 0.f;
            for (int c = 0; c < CTX; ++c)
                m0 = fmaf(ldin(W1c, r*CTX+c, f32), ldin(b2c, c, f32), m0);
            v = ldin(b1d, r, f32) + ldin(b1c, r, f32) + ldin(b1p, r, f32) + m0;
        } else if (k <= 248) {                   // W1p columns
            v = ldin(W1p, r*2 + (k-247), f32);
        }
    } else if (r < 246) {                        // out rows
        int o = r - 240;
        if (k < HID)       v = ldin(W2d, o*HID + k, f32);
        else if (k == 246) v = ldin(b2d, o, f32);
    }
    Aa[idx] = (f16)v;
}

// frag-major Hx offset for scalar element (row j, col n), within one buffer
__device__ __forceinline__ int hx_off(int j, int n) {
    return (j >> 5)*512 + ((((j & 31) >> 3))*16 + n)*8 + (j & 7);
}

// ---------------- per-step MFMA recurrent kernel: 2 blocks x 16 batches ----------------
__global__ __launch_bounds__(512, 2) void rnn_mfma(
    const void* __restrict__ data,   // [30][6][8192]
    const void* __restrict__ b1d, const void* __restrict__ W1p,
    const void* __restrict__ b1p, const void* __restrict__ b1c,
    const void* __restrict__ W1d, const void* __restrict__ pb,
    const f16* __restrict__ Aa, const int* __restrict__ flagp,
    void* __restrict__ out)          // [30][8192][6]
{
    const bool f32 = (*flagp != 0);
    const int tid  = threadIdx.x;
    const int w    = tid >> 6;       // wave 0..7: row-tiles {2w, 2w+1}; wave7 tile15 = out
    const int l    = tid & 63;
    const int n16  = l & 15;
    const int quad = l >> 4;
    const int base = blockIdx.x * 16;
    const int bn   = base + n16;
    const bool bvalid = (bn < 30);
    const long obase = (long)bn * T_STEPS * 6;

    __shared__ __align__(16) f16 Hx[2*HXBUF];        // 16,384 B

    // ---- zero Hx (rows >248 and untouched slots must stay 0)
    {
        int* hz = (int*)Hx;
        for (int i = tid; i < HXBUF; i += 512) hz[i] = 0;    // 4096 ints = both buffers
    }
    __syncthreads();

    // ---- const rows 246/247/248 in both buffers
    // row246 -> frag7,quad'2,j'6 ; row247 -> frag7,quad'2,j'7 ; row248 -> frag7,quad'3,j'0
    if (tid < 32) {
        int bsel = tid >> 4, n = tid & 15;
        int nb = base + n; if (nb > 29) nb = 29;
        f16* buf = Hx + bsel*HXBUF;
        buf[3584 + (32+n)*8 + 6] = (f16)1.0f;
        buf[3584 + (32+n)*8 + 7] = (f16)ldin(pb, nb*2+0, f32);
        buf[3584 + (48+n)*8 + 0] = (f16)ldin(pb, nb*2+1, f32);
    }

    // ---- h_0 = relu(cb + W1d d_0)  into Hx[0]
    for (int p = tid; p < HID*16; p += 512) {
        int n = p / HID, j = p - n*HID;
        int nb = base + n; if (nb > 29) nb = 29;
        float s = ldin(b1d, j, f32) + ldin(b1c, j, f32) + ldin(b1p, j, f32)
                + ldin(W1p, j*2+0, f32)*ldin(pb, nb*2+0, f32)
                + ldin(W1p, j*2+1, f32)*ldin(pb, nb*2+1, f32);
        for (int d = 0; d < 6; ++d)
            s = fmaf(ldin(W1d, j*6+d, f32), ldin(data, ((long)nb*6+d)*T_STEPS, f32), s);
        Hx[hx_off(j, n)] = (f16)fmaxf(s, 0.f);
    }

    // ---- d-feed lane roles (tid<96 = waves 0-1): (pn, pd)
    const int pn = tid & 15, pd = tid >> 4;
    int pnb = base + pn; if (pnb > 29) pnb = 29;
    const long prow = ((long)pnb*6 + (pd < 6 ? pd : 0))*T_STEPS;
    const int  doff = 3584 + (32+pn)*8 + pd;     // row (240+pd), col pn

    // d_1 into Hx[0] rows 240..245
    if (tid < 96)
        Hx[doff] = (f16)ldin(data, prow + 1, f32);

    // d-FIFO preload: u0 = raw d[2] (consumed step 0), u1 = raw d[3] (step 1)
    unsigned u0 = 0, u1 = 0;
    const unsigned esz = f32 ? 4u : 2u;
    unsigned voff = (unsigned)((unsigned long)(prow + 4) * esz);           // d[t+4] @ t=0
    const unsigned vmax = (unsigned)((unsigned long)(prow + T_STEPS-1) * esz);
    if (tid < 96) {
        if (!f32) {
            u0 = ((const unsigned short*)data)[prow + 2];
            u1 = ((const unsigned short*)data)[prow + 3];
        } else {
            u0 = __builtin_bit_cast(unsigned, ((const float*)data)[prow + 2]);
            u1 = __builtin_bit_cast(unsigned, ((const float*)data)[prow + 3]);
        }
    }

    // ---- persistent A fragments: 16 NAMED half8 locals (AGPR-resident)
    const f16* Ab0 = Aa + (size_t)((w*2+0)*16 + n16)*KTOT + quad*8;
    const f16* Ab1 = Aa + (size_t)((w*2+1)*16 + n16)*KTOT + quad*8;
    half8 a00 = *(const half8*)(Ab0 +   0), a01 = *(const half8*)(Ab0 +  32);
    half8 a02 = *(const half8*)(Ab0 +  64), a03 = *(const half8*)(Ab0 +  96);
    half8 a04 = *(const half8*)(Ab0 + 128), a05 = *(const half8*)(Ab0 + 160);
    half8 a06 = *(const half8*)(Ab0 + 192), a07 = *(const half8*)(Ab0 + 224);
    half8 a10 = *(const half8*)(Ab1 +   0), a11 = *(const half8*)(Ab1 +  32);
    half8 a12 = *(const half8*)(Ab1 +  64), a13 = *(const half8*)(Ab1 +  96);
    half8 a14 = *(const half8*)(Ab1 + 128), a15 = *(const half8*)(Ab1 + 160);
    half8 a16 = *(const half8*)(Ab1 + 192), a17 = *(const half8*)(Ab1 + 224);
    // drain A reads before any wave can store into the (possible) d_out-tail scratch
    asm volatile("s_waitcnt vmcnt(0)" ::: "memory");
    __syncthreads();

    // ---- steady-state addressing
    // read: lane-contiguous; cur/frag are compile-time imm offsets
    const f16* hxread0 = Hx + l*8;
    // write: tile 2w at off0, tile 2w+1 at off0+256 (buffer select = +nxt*HXBUF)
    f16* hxw = Hx + w*512 + ((quad>>1)*16 + n16)*8 + 4*(quad&1);

    f32x4 pend = {0.f, 0.f, 0.f, 0.f};           // wave7: out values awaiting store

    for (int t2 = 0; t2 < T_STEPS; t2 += 2) {
        #pragma unroll
        for (int s = 0; s < 2; ++s) {
            const int t = t2 + s;
            const int cur = s, nxt = s ^ 1;      // compile-time parity

            // ---- (1) B fragment reads FIRST: start the LDS-pipe drain at once
            const f16* hxc = hxread0 + cur*HXBUF;
            half8 b0 = *(const half8*)(hxc +    0);
            half8 b1 = *(const half8*)(hxc +  512);
            half8 b2 = *(const half8*)(hxc + 1024);
            half8 b3 = *(const half8*)(hxc + 1536);
            half8 b4 = *(const half8*)(hxc + 2048);
            half8 b5 = *(const half8*)(hxc + 2560);
            half8 b6 = *(const half8*)(hxc + 3072);
            half8 b7 = *(const half8*)(hxc + 3584);

            // ---- (2) bubble fill: deferred out-store for step t-1 (wave 7)
            if (w == 7 && bvalid && (s == 1 || t2 > 0))
                store_out(out, f32, quad, obase + (long)(t-1)*6, pend);

            // ---- bubble fill: d-feed (waves 0-1): d_{t+2} -> Hx[nxt]; load d[t+4]
            if (tid < 96) {
                unsigned uc = (s == 0) ? u0 : u1;
                float dv = f32 ? __builtin_bit_cast(float, uc)
                               : __builtin_bit_cast(float, uc << 16);
                Hx[nxt*HXBUF + doff] = (f16)dv;
                unsigned un;
                if (!f32) un = *(const unsigned short*)((const char*)data + voff);
                else      un = __builtin_bit_cast(unsigned, *(const float*)((const char*)data + voff));
                unsigned vn = voff + esz;
                voff = (vn > vmax) ? vmax : vn;
                if (s == 0) u0 = un; else u1 = un;
            }

            // ---- (3) MFMA: c0 frags 0..7, c1 rotated 1..7,0 (c0 finishes early)
            f32x4 c0 = {0.f,0.f,0.f,0.f}, c1 = {0.f,0.f,0.f,0.f};
            c0 = MFMA16(a00, b0, c0);
            c1 = MFMA16(a11, b1, c1);
            c0 = MFMA16(a01, b1, c0);
            c1 = MFMA16(a12, b2, c1);
            c0 = MFMA16(a02, b2, c0);
            c1 = MFMA16(a13, b3, c1);
            c0 = MFMA16(a03, b3, c0);
            c1 = MFMA16(a14, b4, c1);
            c0 = MFMA16(a04, b4, c0);
            c1 = MFMA16(a15, b5, c1);
            c0 = MFMA16(a05, b5, c0);
            c1 = MFMA16(a16, b6, c1);
            c0 = MFMA16(a06, b6, c0);
            c1 = MFMA16(a17, b7, c1);
            c0 = MFMA16(a07, b7, c0);

            // ---- epilogue c0 (tile 2w, always h): overlaps c1's last MFMA
            f16* hxn = hxw + nxt*HXBUF;
            {
                half4v hv;
                hv.x = (f16)fmaxf(c0.x, 0.f);
                hv.y = (f16)fmaxf(c0.y, 0.f);
                hv.z = (f16)fmaxf(c0.z, 0.f);
                hv.w = (f16)fmaxf(c0.w, 0.f);
                *(half4v*)(hxn) = hv;
            }
            c1 = MFMA16(a10, b0, c1);            // c1's final (rotated) MFMA

            // ---- epilogue c1: h-tile for waves 0-6; wave 7 defers out to t+1
            if (w < 7) {                         // tile 2w+1: h-tile
                half4v hv;
                hv.x = (f16)fmaxf(c1.x, 0.f);
                hv.y = (f16)fmaxf(c1.y, 0.f);
                hv.z = (f16)fmaxf(c1.z, 0.f);
                hv.w = (f16)fmaxf(c1.w, 0.f);
                *(half4v*)(hxn + 256) = hv;
            } else {
                pend = c1;                       // stored in next step's bubble
            }
            barrier_lds();                       // lgkmcnt only -- vmem stays in flight
        }
    }

    // ---- final flush: out for t = T_STEPS-1
    if (w == 7 && bvalid)
        store_out(out, f32, quad, obase + (long)(T_STEPS-1)*6, pend);
}

extern "C" void kernel_launch(void* const* d_in, const int* in_sizes, int n_in,
                              void* d_out, int out_size, void* d_ws, size_t ws_size,
                              hipStream_t stream) {
    const void* data = d_in[0];
    const void* W1d  = d_in[1];
    const void* b1d  = d_in[2];
    const void* W1p  = d_in[3];
    const void* b1p  = d_in[4];
    const void* W1c  = d_in[5];
    const void* b1c  = d_in[6];
    const void* W2d  = d_in[7];
    const void* b2d  = d_in[8];
    const void* W2c  = d_in[9];
    const void* b2c  = d_in[10];
    const void* pb   = d_in[11];

    size_t need = SCRATCH_BYTES;
    char* scratch;
    if (ws_size >= need) {
        scratch = (char*)d_ws;
    } else {
        size_t out_bytes = (size_t)30*T_STEPS*6*sizeof(bf16);
        scratch = (char*)d_out + ((out_bytes - need) & ~(size_t)255);
    }
    f16* Aa    = (f16*)scratch;
    int* flagp = (int*)(scratch + A_HALVES*2);

    detect_dtype<<<1, 64, 0, stream>>>(data, flagp);
    build_A<<<A_HALVES/256, 256, 0, stream>>>(W1d, b1d, W1p, b1p, W1c, b1c,
                                              W2d, b2d, W2c, b2c, Aa, flagp);
    rnn_mfma<<<2, 512, 0, stream>>>(data, b1d, W1p, b1p, b1c, W1d, pb,
                                    Aa, flagp, d_out);
}